// Round 10
// baseline (877.217 us; speedup 1.0000x reference)
//
#include <hip/hip_runtime.h>
#include <math.h>

#define BB 8
#define NN 1024
#define DD 64
#define EPSF 0.05f
#define MAX_ITER 100
// 1/(eps*ln2) and eps*ln2
#define SCALE_ 28.853900817779268f
#define EPSLN2_ 0.034657359027997264f
#define NBLK 256
#define NPER 32   // blocks per batch barrier

typedef __attribute__((ext_vector_type(8))) short short8;
typedef __attribute__((ext_vector_type(4))) float f32x4;

static __device__ __forceinline__ float fexp2(float x) { return __builtin_amdgcn_exp2f(x); }
static __device__ __forceinline__ float flog2(float x) { return __builtin_amdgcn_logf(x); }
static __device__ __forceinline__ float bflo(unsigned u) { return __uint_as_float(u << 16); }
static __device__ __forceinline__ unsigned short bf16rne(float x) {
    unsigned u = __float_as_uint(x);
    u += 0x7fffu + ((u >> 16) & 1u);
    return (unsigned short)(u >> 16);
}
__device__ __forceinline__ float wave_sum64(float x) {
#pragma unroll
    for (int off = 1; off < 64; off <<= 1) x += __shfl_xor(x, off);
    return x;
}

// ---- metadata layout unchanged from R9 (err/pub regions allocated but now unused;
//      early-break is provably dead: contraction 1-1.6e-8/iter, err starts ~2800x thresh) ----
#define CNTIDX(p, b) ((b) * 256 + (p))   // cnt: 2048 u32

// ---------------- fused normalize + cost + exp via MFMA (verbatim R9-proven) ----------------
__global__ __launch_bounds__(256) void cost_kernel(const float* __restrict__ q,
                                                   const float* __restrict__ k,
                                                   unsigned short* __restrict__ M,
                                                   unsigned short* __restrict__ MT) {
    __shared__ __align__(16) float Qs[64][65];
    __shared__ __align__(16) float Ks[64][65];
    __shared__ float qin[64];
    __shared__ float kin[64];
    __shared__ __align__(16) unsigned short Qb[64][72];   // pitch 72: 2-way conflict = free
    __shared__ __align__(16) unsigned short Kb[64][72];
    int b = blockIdx.z;
    int i0 = blockIdx.y * 64, j0 = blockIdx.x * 64;
    const float* Qp = q + ((size_t)b * NN + i0) * DD;
    const float* Kp = k + ((size_t)b * NN + j0) * DD;
    int tid = threadIdx.x;
#pragma unroll
    for (int kk = 0; kk < 4; ++kk) {
        int c = tid + 256 * kk;
        int row = c >> 4;
        int c4 = c & 15;
        float4 qv = ((const float4*)(Qp + row * DD))[c4];
        Qs[row][c4 * 4 + 0] = qv.x; Qs[row][c4 * 4 + 1] = qv.y;
        Qs[row][c4 * 4 + 2] = qv.z; Qs[row][c4 * 4 + 3] = qv.w;
        float4 kv = ((const float4*)(Kp + row * DD))[c4];
        Ks[row][c4 * 4 + 0] = kv.x; Ks[row][c4 * 4 + 1] = kv.y;
        Ks[row][c4 * 4 + 2] = kv.z; Ks[row][c4 * 4 + 3] = kv.w;
    }
    __syncthreads();
    if (tid < 64) {
        float ss = 0.f;
#pragma unroll 16
        for (int d = 0; d < 64; ++d) ss += Qs[tid][d] * Qs[tid][d];
        qin[tid] = 1.0f / fmaxf(sqrtf(ss), 1e-12f);
    } else if (tid < 128) {
        int r = tid - 64;
        float ss = 0.f;
#pragma unroll 16
        for (int d = 0; d < 64; ++d) ss += Ks[r][d] * Ks[r][d];
        kin[r] = 1.0f / fmaxf(sqrtf(ss), 1e-12f);
    }
    __syncthreads();
    {
        int row = tid >> 2, d0 = (tid & 3) * 16;
        float qs = qin[row], ks = kin[row];
#pragma unroll
        for (int p = 0; p < 4; ++p) {
            int d = d0 + p * 4;
            uint2 t;
            t.x = (unsigned)bf16rne(Qs[row][d + 0] * qs) | ((unsigned)bf16rne(Qs[row][d + 1] * qs) << 16);
            t.y = (unsigned)bf16rne(Qs[row][d + 2] * qs) | ((unsigned)bf16rne(Qs[row][d + 3] * qs) << 16);
            *(uint2*)&Qb[row][d] = t;
            t.x = (unsigned)bf16rne(Ks[row][d + 0] * ks) | ((unsigned)bf16rne(Ks[row][d + 1] * ks) << 16);
            t.y = (unsigned)bf16rne(Ks[row][d + 2] * ks) | ((unsigned)bf16rne(Ks[row][d + 3] * ks) << 16);
            *(uint2*)&Kb[row][d] = t;
        }
    }
    __syncthreads();
    int w = tid >> 6, lane = tid & 63;
    int m = lane & 15, qq = lane >> 4;
    int rloc = w * 16;
    short8 a0 = *(const short8*)&Qb[rloc + m][qq * 8];
    short8 a1 = *(const short8*)&Qb[rloc + m][qq * 8 + 32];
    f32x4 acc[4];
#pragma unroll
    for (int nt = 0; nt < 4; ++nt) {
        short8 b0 = *(const short8*)&Kb[nt * 16 + m][qq * 8];
        short8 b1 = *(const short8*)&Kb[nt * 16 + m][qq * 8 + 32];
        f32x4 z = {0.f, 0.f, 0.f, 0.f};
        z = __builtin_amdgcn_mfma_f32_16x16x32_bf16(a0, b0, z, 0, 0, 0);
        acc[nt] = __builtin_amdgcn_mfma_f32_16x16x32_bf16(a1, b1, z, 0, 0, 0);
    }
#pragma unroll
    for (int nt = 0; nt < 4; ++nt) {
        int gj = j0 + nt * 16 + m;
        unsigned short us[4];
#pragma unroll
        for (int r = 0; r < 4; ++r)
            us[r] = bf16rne(fexp2((acc[nt][r] - 1.0f) * SCALE_));
#pragma unroll
        for (int r = 0; r < 4; ++r)
            M[((size_t)b << 20) + ((size_t)(i0 + rloc + qq * 4 + r) << 10) + gj] = us[r];
        uint2 t;
        t.x = (unsigned)us[0] | ((unsigned)us[1] << 16);
        t.y = (unsigned)us[2] | ((unsigned)us[3] << 16);
        *(uint2*)(MT + ((size_t)b << 20) + ((size_t)gj << 10) + i0 + rloc + qq * 4) = t;
    }
}

// ---------------- persistent Sinkhorn: fixed 100 iterations, no convergence test ----------------
// Early-break machinery removed: with eps=0.05 and cost diameter ~2, the Hilbert
// contraction is 1-1.6e-8/iter; err_sum starts ~2800x threshold and cannot cross it
// in 100 iters. (Even if it could, extra iterations move u,v by <1e-6 — harmless.)
#define ACC8(U4, base)                                              \
    s0 = fmaf(bflo(U4.x), wrg[base + 0], s0);                       \
    s1 = fmaf(__uint_as_float(U4.x), wrg[base + 1], s1);            \
    s0 = fmaf(bflo(U4.y), wrg[base + 2], s0);                       \
    s1 = fmaf(__uint_as_float(U4.y), wrg[base + 3], s1);            \
    s0 = fmaf(bflo(U4.z), wrg[base + 4], s0);                       \
    s1 = fmaf(__uint_as_float(U4.z), wrg[base + 5], s1);            \
    s0 = fmaf(bflo(U4.w), wrg[base + 6], s0);                       \
    s1 = fmaf(__uint_as_float(U4.w), wrg[base + 7], s1);

__global__ __launch_bounds__(256, 1) void sink_coop(const unsigned short* __restrict__ M,
                                                    const unsigned short* __restrict__ MT,
                                                    float* __restrict__ u,
                                                    float* __restrict__ v,
                                                    unsigned* __restrict__ cnt,
                                                    float eln) {
    __shared__ __align__(16) float sw[1280];   // pitch-20 padded
    int tid = threadIdx.x;
    int w = tid >> 6, lane = tid & 63;
    int b = blockIdx.x & 7;
    int slice = blockIdx.x >> 3;          // 0..31
    int rbase = slice * 32 + w * 8;       // wave's first local row
    const unsigned short* Mb  = M  + ((size_t)b << 20);
    const unsigned short* MTb = MT + ((size_t)b << 20);
    float* ub = u + (b << 10);
    float* vb = v + (b << 10);

    // ---- preload this wave's 8 M-rows + 8 MT-rows into registers ----
    uint4 mA[8], mB[8], nA[8], nB[8];
#pragma unroll
    for (int r = 0; r < 8; ++r) {
        const uint4* rp = (const uint4*)(Mb + ((size_t)(rbase + r) << 10));
        mA[r] = rp[lane * 2];
        mB[r] = rp[lane * 2 + 1];
        const uint4* tp = (const uint4*)(MTb + ((size_t)(rbase + r) << 10));
        nA[r] = tp[lane * 2];
        nB[r] = tp[lane * 2 + 1];
    }

    for (int t = 0; t < MAX_ITER; ++t) {
        // ---------- u phase ----------
        {
            float4 ex;
            ex.x = fexp2(__hip_atomic_load(vb + tid * 4 + 0, __ATOMIC_RELAXED, __HIP_MEMORY_SCOPE_AGENT) * SCALE_);
            ex.y = fexp2(__hip_atomic_load(vb + tid * 4 + 1, __ATOMIC_RELAXED, __HIP_MEMORY_SCOPE_AGENT) * SCALE_);
            ex.z = fexp2(__hip_atomic_load(vb + tid * 4 + 2, __ATOMIC_RELAXED, __HIP_MEMORY_SCOPE_AGENT) * SCALE_);
            ex.w = fexp2(__hip_atomic_load(vb + tid * 4 + 3, __ATOMIC_RELAXED, __HIP_MEMORY_SCOPE_AGENT) * SCALE_);
            *(float4*)&sw[tid * 4 + 4 * (tid >> 2)] = ex;
            __syncthreads();
            float wrg[16];
            *(float4*)&wrg[0]  = *(const float4*)&sw[lane * 20 + 0];
            *(float4*)&wrg[4]  = *(const float4*)&sw[lane * 20 + 4];
            *(float4*)&wrg[8]  = *(const float4*)&sw[lane * 20 + 8];
            *(float4*)&wrg[12] = *(const float4*)&sw[lane * 20 + 12];
#pragma unroll
            for (int rr = 0; rr < 8; ++rr) {
                float s0 = 0.f, s1 = 0.f;
                ACC8(mA[rr], 0)
                ACC8(mB[rr], 8)
                float s = wave_sum64(s0 + s1);
                float un = eln - EPSLN2_ * flog2(s);
                if (lane == 0)
                    __hip_atomic_store(ub + rbase + rr, un, __ATOMIC_RELAXED, __HIP_MEMORY_SCOPE_AGENT);
            }
            asm volatile("s_waitcnt vmcnt(0)" ::: "memory");   // drain this wave's u stores
            __syncthreads();
            if (tid == 0) {
                unsigned* c = cnt + CNTIDX(2 * t, b);
                __hip_atomic_fetch_add(c, 1u, __ATOMIC_RELAXED, __HIP_MEMORY_SCOPE_AGENT);
                while (__hip_atomic_load(c, __ATOMIC_RELAXED, __HIP_MEMORY_SCOPE_AGENT) < NPER)
                    __builtin_amdgcn_s_sleep(1);
            }
            __syncthreads();
        }
        // ---------- v phase ----------
        {
            float4 ex;
            ex.x = fexp2(__hip_atomic_load(ub + tid * 4 + 0, __ATOMIC_RELAXED, __HIP_MEMORY_SCOPE_AGENT) * SCALE_);
            ex.y = fexp2(__hip_atomic_load(ub + tid * 4 + 1, __ATOMIC_RELAXED, __HIP_MEMORY_SCOPE_AGENT) * SCALE_);
            ex.z = fexp2(__hip_atomic_load(ub + tid * 4 + 2, __ATOMIC_RELAXED, __HIP_MEMORY_SCOPE_AGENT) * SCALE_);
            ex.w = fexp2(__hip_atomic_load(ub + tid * 4 + 3, __ATOMIC_RELAXED, __HIP_MEMORY_SCOPE_AGENT) * SCALE_);
            *(float4*)&sw[tid * 4 + 4 * (tid >> 2)] = ex;
            __syncthreads();
            float wrg[16];
            *(float4*)&wrg[0]  = *(const float4*)&sw[lane * 20 + 0];
            *(float4*)&wrg[4]  = *(const float4*)&sw[lane * 20 + 4];
            *(float4*)&wrg[8]  = *(const float4*)&sw[lane * 20 + 8];
            *(float4*)&wrg[12] = *(const float4*)&sw[lane * 20 + 12];
#pragma unroll
            for (int rr = 0; rr < 8; ++rr) {
                float s0 = 0.f, s1 = 0.f;
                ACC8(nA[rr], 0)
                ACC8(nB[rr], 8)
                float s = wave_sum64(s0 + s1);
                float vn = eln - EPSLN2_ * flog2(s);
                if (lane == 0)
                    __hip_atomic_store(vb + rbase + rr, vn, __ATOMIC_RELAXED, __HIP_MEMORY_SCOPE_AGENT);
            }
            asm volatile("s_waitcnt vmcnt(0)" ::: "memory");   // drain this wave's v stores
            __syncthreads();
            if (tid == 0) {
                unsigned* c = cnt + CNTIDX(2 * t + 1, b);
                __hip_atomic_fetch_add(c, 1u, __ATOMIC_RELAXED, __HIP_MEMORY_SCOPE_AGENT);
                while (__hip_atomic_load(c, __ATOMIC_RELAXED, __HIP_MEMORY_SCOPE_AGENT) < NPER)
                    __builtin_amdgcn_s_sleep(1);
            }
            __syncthreads();
        }
    }
}

// ---------------- WT precompute: WT[b][d][j] = bf16( exp2(v_j*S) * V[b][j][d] ) ----------------
__global__ __launch_bounds__(256) void wt_kernel(const float* __restrict__ V,
                                                 const float* __restrict__ v,
                                                 unsigned short* __restrict__ WT) {
    __shared__ __align__(16) float Vs[64][65];
    __shared__ float wj[64];
    int b = blockIdx.x & 7, jt = blockIdx.x >> 3;
    int j0 = jt * 64;
    int tid = threadIdx.x;
    const float* Vb = V + ((size_t)b << 16) + ((size_t)j0 << 6);
#pragma unroll
    for (int c = 0; c < 4; ++c) {
        int idx = tid + 256 * c;
        int row = idx >> 4, c4 = idx & 15;
        float4 x = ((const float4*)(Vb + row * 64))[c4];
        Vs[row][c4 * 4 + 0] = x.x; Vs[row][c4 * 4 + 1] = x.y;
        Vs[row][c4 * 4 + 2] = x.z; Vs[row][c4 * 4 + 3] = x.w;
    }
    if (tid < 64) wj[tid] = fexp2(v[(b << 10) + j0 + tid] * SCALE_);
    __syncthreads();
    int d = tid >> 2, qd = tid & 3;
    unsigned pk[8];
#pragma unroll
    for (int p = 0; p < 8; ++p) {
        int j = qd * 16 + p * 2;
        unsigned lo = bf16rne(Vs[j][d] * wj[j]);
        unsigned hi = bf16rne(Vs[j + 1][d] * wj[j + 1]);
        pk[p] = lo | (hi << 16);
    }
    unsigned short* dst = WT + ((size_t)b << 16) + ((size_t)d << 10) + j0 + qd * 16;
    ((uint4*)dst)[0] = make_uint4(pk[0], pk[1], pk[2], pk[3]);
    ((uint4*)dst)[1] = make_uint4(pk[4], pk[5], pk[6], pk[7]);
}

// ---------------- MFMA epilogue: out = diag(a) * (M @ W) + V ----------------
__global__ __launch_bounds__(256) void gemm_final(const unsigned short* __restrict__ M,
                                                  const unsigned short* __restrict__ WT,
                                                  const float* __restrict__ u,
                                                  const float* __restrict__ V,
                                                  float* __restrict__ out) {
    __shared__ float sa[32];
    int tid = threadIdx.x;
    int w = tid >> 6, lane = tid & 63;
    int b = blockIdx.x & 7, mt = blockIdx.x >> 3;
    if (tid < 32) sa[tid] = fexp2(u[(b << 10) + mt * 32 + tid] * SCALE_);
    __syncthreads();
    int m = lane & 15, q = lane >> 4;
    int rloc = (w & 1) * 16;
    int nbase = (w >> 1) * 32;
    const unsigned short* Ma = M + ((size_t)b << 20) + ((size_t)(mt * 32 + rloc + m) << 10) + q * 8;
    const unsigned short* W0 = WT + ((size_t)b << 16) + ((size_t)(nbase + m) << 10) + q * 8;
    const unsigned short* W1 = W0 + (16 << 10);
    f32x4 acc0 = {0.f, 0.f, 0.f, 0.f}, acc1 = {0.f, 0.f, 0.f, 0.f};
#pragma unroll 4
    for (int k0 = 0; k0 < NN; k0 += 32) {
        short8 af = *(const short8*)(Ma + k0);
        short8 b0 = *(const short8*)(W0 + k0);
        short8 b1 = *(const short8*)(W1 + k0);
        acc0 = __builtin_amdgcn_mfma_f32_16x16x32_bf16(af, b0, acc0, 0, 0, 0);
        acc1 = __builtin_amdgcn_mfma_f32_16x16x32_bf16(af, b1, acc1, 0, 0, 0);
    }
#pragma unroll
    for (int r = 0; r < 4; ++r) {
        int lrow = rloc + q * 4 + r;
        int gm = mt * 32 + lrow;
        float a = sa[lrow];
        size_t base = (((size_t)b << 10) + gm) * DD;
        int n0 = nbase + m;
        out[base + n0]      = fmaf(a, acc0[r], V[base + n0]);
        out[base + n0 + 16] = fmaf(a, acc1[r], V[base + n0 + 16]);
    }
}

extern "C" void kernel_launch(void* const* d_in, const int* in_sizes, int n_in,
                              void* d_out, int out_size, void* d_ws, size_t ws_size,
                              hipStream_t stream) {
    const float* q = (const float*)d_in[0];
    const float* k = (const float*)d_in[1];
    const float* V = (const float*)d_in[2];
    float* out = (float*)d_out;

    char* ws = (char*)d_ws;
    const size_t MB16 = (size_t)BB * NN * NN * sizeof(unsigned short);   // 16 MB
    unsigned short* M  = (unsigned short*)ws;
    unsigned short* MT = (unsigned short*)(ws + MB16);
    unsigned short* WT = MT;                  // MT is dead after sink; reuse (1 MB)
    float* u   = (float*)(ws + 2 * MB16);
    float* v   = u + BB * NN;                 // 8192 floats
    float* err = v + BB * NN;                 // 1024 floats (unused, kept for layout)
    unsigned* cnt = (unsigned*)(err + 1024);  // 2048 u32 (b*256+p)

    size_t zbytes = (size_t)(2 * BB * NN + 1024 + 2048 + 128) * 4;
    hipMemsetAsync(u, 0, zbytes, stream);

    cost_kernel<<<dim3(16, 16, 8), 256, 0, stream>>>(q, k, M, MT);

    float eln = EPSF * logf(1.0f / NN + 1e-8f);
    void* args[6];
    args[0] = &M; args[1] = &MT; args[2] = &u; args[3] = &v;
    args[4] = &cnt; args[5] = &eln;
    hipLaunchCooperativeKernel((const void*)sink_coop, dim3(NBLK), dim3(256),
                               args, 0, stream);

    wt_kernel<<<128, 256, 0, stream>>>(V, v, WT);
    gemm_final<<<256, 256, 0, stream>>>(M, WT, u, V, out);
}

// Round 11
// 189.851 us; speedup vs baseline: 4.6206x; 4.6206x over previous
//
#include <hip/hip_runtime.h>
#include <math.h>

#define BB 8
#define NN 1024
#define DD 64
#define EPSF 0.05f
#define MAX_ITER 100
// threshold on SUM of |du| over B*N (reference: mean < 1e-6)
#define ERR_SUM_THRESH 8.192e-3f
// 1/(eps*ln2) and eps*ln2
#define SCALE_ 28.853900817779268f
#define EPSLN2_ 0.034657359027997264f
#define NBLK 256
#define NPER 32   // blocks per batch barrier

typedef __attribute__((ext_vector_type(8))) short short8;
typedef __attribute__((ext_vector_type(4))) float f32x4;

static __device__ __forceinline__ float fexp2(float x) { return __builtin_amdgcn_exp2f(x); }
static __device__ __forceinline__ float flog2(float x) { return __builtin_amdgcn_logf(x); }
static __device__ __forceinline__ float bflo(unsigned u) { return __uint_as_float(u << 16); }
static __device__ __forceinline__ unsigned short bf16rne(float x) {
    unsigned u = __float_as_uint(x);
    u += 0x7fffu + ((u >> 16) & 1u);
    return (unsigned short)(u >> 16);
}
__device__ __forceinline__ float wave_sum64(float x) {
#pragma unroll
    for (int off = 1; off < 64; off <<= 1) x += __shfl_xor(x, off);
    return x;
}

// ---- compact metadata layout: 78,336 B past the two 16MB matrices (R3-proven bound) ----
#define ERRIDX(t, b) ((b) * 128 + (t))   // err: 1024 floats
#define CNTIDX(p, b) ((b) * 256 + (p))   // cnt: 2048 u32
#define PUBIDX(t) (t)                    // pub: 128 u32

// ---------------- fused normalize + cost + exp via MFMA (verbatim R9-proven) ----------------
__global__ __launch_bounds__(256) void cost_kernel(const float* __restrict__ q,
                                                   const float* __restrict__ k,
                                                   unsigned short* __restrict__ M,
                                                   unsigned short* __restrict__ MT) {
    __shared__ __align__(16) float Qs[64][65];
    __shared__ __align__(16) float Ks[64][65];
    __shared__ float qin[64];
    __shared__ float kin[64];
    __shared__ __align__(16) unsigned short Qb[64][72];   // pitch 72: 2-way conflict = free
    __shared__ __align__(16) unsigned short Kb[64][72];
    int b = blockIdx.z;
    int i0 = blockIdx.y * 64, j0 = blockIdx.x * 64;
    const float* Qp = q + ((size_t)b * NN + i0) * DD;
    const float* Kp = k + ((size_t)b * NN + j0) * DD;
    int tid = threadIdx.x;
#pragma unroll
    for (int kk = 0; kk < 4; ++kk) {
        int c = tid + 256 * kk;
        int row = c >> 4;
        int c4 = c & 15;
        float4 qv = ((const float4*)(Qp + row * DD))[c4];
        Qs[row][c4 * 4 + 0] = qv.x; Qs[row][c4 * 4 + 1] = qv.y;
        Qs[row][c4 * 4 + 2] = qv.z; Qs[row][c4 * 4 + 3] = qv.w;
        float4 kv = ((const float4*)(Kp + row * DD))[c4];
        Ks[row][c4 * 4 + 0] = kv.x; Ks[row][c4 * 4 + 1] = kv.y;
        Ks[row][c4 * 4 + 2] = kv.z; Ks[row][c4 * 4 + 3] = kv.w;
    }
    __syncthreads();
    if (tid < 64) {
        float ss = 0.f;
#pragma unroll 16
        for (int d = 0; d < 64; ++d) ss += Qs[tid][d] * Qs[tid][d];
        qin[tid] = 1.0f / fmaxf(sqrtf(ss), 1e-12f);
    } else if (tid < 128) {
        int r = tid - 64;
        float ss = 0.f;
#pragma unroll 16
        for (int d = 0; d < 64; ++d) ss += Ks[r][d] * Ks[r][d];
        kin[r] = 1.0f / fmaxf(sqrtf(ss), 1e-12f);
    }
    __syncthreads();
    {
        int row = tid >> 2, d0 = (tid & 3) * 16;
        float qs = qin[row], ks = kin[row];
#pragma unroll
        for (int p = 0; p < 4; ++p) {
            int d = d0 + p * 4;
            uint2 t;
            t.x = (unsigned)bf16rne(Qs[row][d + 0] * qs) | ((unsigned)bf16rne(Qs[row][d + 1] * qs) << 16);
            t.y = (unsigned)bf16rne(Qs[row][d + 2] * qs) | ((unsigned)bf16rne(Qs[row][d + 3] * qs) << 16);
            *(uint2*)&Qb[row][d] = t;
            t.x = (unsigned)bf16rne(Ks[row][d + 0] * ks) | ((unsigned)bf16rne(Ks[row][d + 1] * ks) << 16);
            t.y = (unsigned)bf16rne(Ks[row][d + 2] * ks) | ((unsigned)bf16rne(Ks[row][d + 3] * ks) << 16);
            *(uint2*)&Kb[row][d] = t;
        }
    }
    __syncthreads();
    int w = tid >> 6, lane = tid & 63;
    int m = lane & 15, qq = lane >> 4;
    int rloc = w * 16;
    short8 a0 = *(const short8*)&Qb[rloc + m][qq * 8];
    short8 a1 = *(const short8*)&Qb[rloc + m][qq * 8 + 32];
    f32x4 acc[4];
#pragma unroll
    for (int nt = 0; nt < 4; ++nt) {
        short8 b0 = *(const short8*)&Kb[nt * 16 + m][qq * 8];
        short8 b1 = *(const short8*)&Kb[nt * 16 + m][qq * 8 + 32];
        f32x4 z = {0.f, 0.f, 0.f, 0.f};
        z = __builtin_amdgcn_mfma_f32_16x16x32_bf16(a0, b0, z, 0, 0, 0);
        acc[nt] = __builtin_amdgcn_mfma_f32_16x16x32_bf16(a1, b1, z, 0, 0, 0);
    }
#pragma unroll
    for (int nt = 0; nt < 4; ++nt) {
        int gj = j0 + nt * 16 + m;
        unsigned short us[4];
#pragma unroll
        for (int r = 0; r < 4; ++r)
            us[r] = bf16rne(fexp2((acc[nt][r] - 1.0f) * SCALE_));
#pragma unroll
        for (int r = 0; r < 4; ++r)
            M[((size_t)b << 20) + ((size_t)(i0 + rloc + qq * 4 + r) << 10) + gj] = us[r];
        uint2 t;
        t.x = (unsigned)us[0] | ((unsigned)us[1] << 16);
        t.y = (unsigned)us[2] | ((unsigned)us[3] << 16);
        *(uint2*)(MT + ((size_t)b << 20) + ((size_t)gj << 10) + i0 + rloc + qq * 4) = t;
    }
}

// ---------------- persistent Sinkhorn (verbatim R9-proven, incl. err/pub machinery;
// R10 showed removing it wrecks barrier dynamics — it is load-bearing) ----------------
#define ACC8(U4, base)                                              \
    s0 = fmaf(bflo(U4.x), wrg[base + 0], s0);                       \
    s1 = fmaf(__uint_as_float(U4.x), wrg[base + 1], s1);            \
    s0 = fmaf(bflo(U4.y), wrg[base + 2], s0);                       \
    s1 = fmaf(__uint_as_float(U4.y), wrg[base + 3], s1);            \
    s0 = fmaf(bflo(U4.z), wrg[base + 4], s0);                       \
    s1 = fmaf(__uint_as_float(U4.z), wrg[base + 5], s1);            \
    s0 = fmaf(bflo(U4.w), wrg[base + 6], s0);                       \
    s1 = fmaf(__uint_as_float(U4.w), wrg[base + 7], s1);

__global__ __launch_bounds__(256, 1) void sink_coop(const unsigned short* __restrict__ M,
                                                    const unsigned short* __restrict__ MT,
                                                    float* __restrict__ u,
                                                    float* __restrict__ v,
                                                    float* __restrict__ err,
                                                    unsigned* __restrict__ cnt,
                                                    unsigned* __restrict__ pub,
                                                    float eln) {
    __shared__ __align__(16) float sw[1280];   // pitch-20 padded
    __shared__ float sdel[4];
    __shared__ int sflag;
    int tid = threadIdx.x;
    int w = tid >> 6, lane = tid & 63;
    int b = blockIdx.x & 7;
    int slice = blockIdx.x >> 3;          // 0..31
    int rbase = slice * 32 + w * 8;       // wave's first local row
    const unsigned short* Mb  = M  + ((size_t)b << 20);
    const unsigned short* MTb = MT + ((size_t)b << 20);
    float* ub = u + (b << 10);
    float* vb = v + (b << 10);

    // ---- preload this wave's 8 M-rows + 8 MT-rows into registers ----
    uint4 mA[8], mB[8], nA[8], nB[8];
#pragma unroll
    for (int r = 0; r < 8; ++r) {
        const uint4* rp = (const uint4*)(Mb + ((size_t)(rbase + r) << 10));
        mA[r] = rp[lane * 2];
        mB[r] = rp[lane * 2 + 1];
        const uint4* tp = (const uint4*)(MTb + ((size_t)(rbase + r) << 10));
        nA[r] = tp[lane * 2];
        nB[r] = tp[lane * 2 + 1];
    }

    float uprev[8];
#pragma unroll
    for (int r = 0; r < 8; ++r) uprev[r] = 0.f;

    for (int t = 0; t < MAX_ITER; ++t) {
        // ---------- u phase ----------
        {
            float4 ex;
            ex.x = fexp2(__hip_atomic_load(vb + tid * 4 + 0, __ATOMIC_RELAXED, __HIP_MEMORY_SCOPE_AGENT) * SCALE_);
            ex.y = fexp2(__hip_atomic_load(vb + tid * 4 + 1, __ATOMIC_RELAXED, __HIP_MEMORY_SCOPE_AGENT) * SCALE_);
            ex.z = fexp2(__hip_atomic_load(vb + tid * 4 + 2, __ATOMIC_RELAXED, __HIP_MEMORY_SCOPE_AGENT) * SCALE_);
            ex.w = fexp2(__hip_atomic_load(vb + tid * 4 + 3, __ATOMIC_RELAXED, __HIP_MEMORY_SCOPE_AGENT) * SCALE_);
            *(float4*)&sw[tid * 4 + 4 * (tid >> 2)] = ex;
            __syncthreads();
            float wrg[16];
            *(float4*)&wrg[0]  = *(const float4*)&sw[lane * 20 + 0];
            *(float4*)&wrg[4]  = *(const float4*)&sw[lane * 20 + 4];
            *(float4*)&wrg[8]  = *(const float4*)&sw[lane * 20 + 8];
            *(float4*)&wrg[12] = *(const float4*)&sw[lane * 20 + 12];
            float del = 0.f;
#pragma unroll
            for (int rr = 0; rr < 8; ++rr) {
                float s0 = 0.f, s1 = 0.f;
                ACC8(mA[rr], 0)
                ACC8(mB[rr], 8)
                float s = wave_sum64(s0 + s1);
                float un = eln - EPSLN2_ * flog2(s);
                del += fabsf(un - uprev[rr]);
                uprev[rr] = un;
                if (lane == 0)
                    __hip_atomic_store(ub + rbase + rr, un, __ATOMIC_RELAXED, __HIP_MEMORY_SCOPE_AGENT);
            }
            if (lane == 0) sdel[w] = del;
            asm volatile("s_waitcnt vmcnt(0)" ::: "memory");
            __syncthreads();
            if (tid == 0) {
                __hip_atomic_fetch_add(err + ERRIDX(t, b), sdel[0] + sdel[1] + sdel[2] + sdel[3],
                                       __ATOMIC_RELAXED, __HIP_MEMORY_SCOPE_AGENT);
                asm volatile("s_waitcnt vmcnt(0)" ::: "memory");
                unsigned* c = cnt + CNTIDX(2 * t, b);
                __hip_atomic_fetch_add(c, 1u, __ATOMIC_RELAXED, __HIP_MEMORY_SCOPE_AGENT);
                while (__hip_atomic_load(c, __ATOMIC_RELAXED, __HIP_MEMORY_SCOPE_AGENT) < NPER)
                    __builtin_amdgcn_s_sleep(1);
                if (slice == 0) {
                    asm volatile("s_waitcnt vmcnt(0)" ::: "memory");
                    __hip_atomic_fetch_add(pub + PUBIDX(t), 1u, __ATOMIC_RELAXED, __HIP_MEMORY_SCOPE_AGENT);
                }
            }
            __syncthreads();
        }
        // ---------- v phase ----------
        {
            float4 ex;
            ex.x = fexp2(__hip_atomic_load(ub + tid * 4 + 0, __ATOMIC_RELAXED, __HIP_MEMORY_SCOPE_AGENT) * SCALE_);
            ex.y = fexp2(__hip_atomic_load(ub + tid * 4 + 1, __ATOMIC_RELAXED, __HIP_MEMORY_SCOPE_AGENT) * SCALE_);
            ex.z = fexp2(__hip_atomic_load(ub + tid * 4 + 2, __ATOMIC_RELAXED, __HIP_MEMORY_SCOPE_AGENT) * SCALE_);
            ex.w = fexp2(__hip_atomic_load(ub + tid * 4 + 3, __ATOMIC_RELAXED, __HIP_MEMORY_SCOPE_AGENT) * SCALE_);
            *(float4*)&sw[tid * 4 + 4 * (tid >> 2)] = ex;
            __syncthreads();
            float wrg[16];
            *(float4*)&wrg[0]  = *(const float4*)&sw[lane * 20 + 0];
            *(float4*)&wrg[4]  = *(const float4*)&sw[lane * 20 + 4];
            *(float4*)&wrg[8]  = *(const float4*)&sw[lane * 20 + 8];
            *(float4*)&wrg[12] = *(const float4*)&sw[lane * 20 + 12];
#pragma unroll
            for (int rr = 0; rr < 8; ++rr) {
                float s0 = 0.f, s1 = 0.f;
                ACC8(nA[rr], 0)
                ACC8(nB[rr], 8)
                float s = wave_sum64(s0 + s1);
                float vn = eln - EPSLN2_ * flog2(s);
                if (lane == 0)
                    __hip_atomic_store(vb + rbase + rr, vn, __ATOMIC_RELAXED, __HIP_MEMORY_SCOPE_AGENT);
            }
            asm volatile("s_waitcnt vmcnt(0)" ::: "memory");
            __syncthreads();
            if (tid == 0) {
                unsigned* c = cnt + CNTIDX(2 * t + 1, b);
                __hip_atomic_fetch_add(c, 1u, __ATOMIC_RELAXED, __HIP_MEMORY_SCOPE_AGENT);
                while (__hip_atomic_load(c, __ATOMIC_RELAXED, __HIP_MEMORY_SCOPE_AGENT) < NPER)
                    __builtin_amdgcn_s_sleep(1);
                float eb = __hip_atomic_load(err + ERRIDX(t, b), __ATOMIC_RELAXED, __HIP_MEMORY_SCOPE_AGENT);
                int brk = 0;
                if (eb < ERR_SUM_THRESH) {
                    while (__hip_atomic_load(pub + PUBIDX(t), __ATOMIC_RELAXED, __HIP_MEMORY_SCOPE_AGENT) < 8u)
                        __builtin_amdgcn_s_sleep(1);
                    float s = 0.f;
                    for (int bb = 0; bb < 8; ++bb)
                        s += __hip_atomic_load(err + ERRIDX(t, bb), __ATOMIC_RELAXED, __HIP_MEMORY_SCOPE_AGENT);
                    brk = (s < ERR_SUM_THRESH);
                }
                sflag = brk;
            }
            __syncthreads();
            if (sflag) break;
        }
    }
}

// ---------------- WT precompute: WT[b][d][j] = bf16( exp2(v_j*S) * V[b][j][d] ) ----------------
__global__ __launch_bounds__(256) void wt_kernel(const float* __restrict__ V,
                                                 const float* __restrict__ v,
                                                 unsigned short* __restrict__ WT) {
    __shared__ __align__(16) float Vs[64][65];
    __shared__ float wj[64];
    int b = blockIdx.x & 7, jt = blockIdx.x >> 3;
    int j0 = jt * 64;
    int tid = threadIdx.x;
    const float* Vb = V + ((size_t)b << 16) + ((size_t)j0 << 6);
#pragma unroll
    for (int c = 0; c < 4; ++c) {
        int idx = tid + 256 * c;
        int row = idx >> 4, c4 = idx & 15;
        float4 x = ((const float4*)(Vb + row * 64))[c4];
        Vs[row][c4 * 4 + 0] = x.x; Vs[row][c4 * 4 + 1] = x.y;
        Vs[row][c4 * 4 + 2] = x.z; Vs[row][c4 * 4 + 3] = x.w;
    }
    if (tid < 64) wj[tid] = fexp2(v[(b << 10) + j0 + tid] * SCALE_);
    __syncthreads();
    int d = tid >> 2, qd = tid & 3;
    unsigned pk[8];
#pragma unroll
    for (int p = 0; p < 8; ++p) {
        int j = qd * 16 + p * 2;
        unsigned lo = bf16rne(Vs[j][d] * wj[j]);
        unsigned hi = bf16rne(Vs[j + 1][d] * wj[j + 1]);
        pk[p] = lo | (hi << 16);
    }
    unsigned short* dst = WT + ((size_t)b << 16) + ((size_t)d << 10) + j0 + qd * 16;
    ((uint4*)dst)[0] = make_uint4(pk[0], pk[1], pk[2], pk[3]);
    ((uint4*)dst)[1] = make_uint4(pk[4], pk[5], pk[6], pk[7]);
}

// ---------------- MFMA epilogue: out = diag(a) * (M @ W) + V ----------------
__global__ __launch_bounds__(256) void gemm_final(const unsigned short* __restrict__ M,
                                                  const unsigned short* __restrict__ WT,
                                                  const float* __restrict__ u,
                                                  const float* __restrict__ V,
                                                  float* __restrict__ out) {
    __shared__ float sa[32];
    int tid = threadIdx.x;
    int w = tid >> 6, lane = tid & 63;
    int b = blockIdx.x & 7, mt = blockIdx.x >> 3;
    if (tid < 32) sa[tid] = fexp2(u[(b << 10) + mt * 32 + tid] * SCALE_);
    __syncthreads();
    int m = lane & 15, q = lane >> 4;
    int rloc = (w & 1) * 16;
    int nbase = (w >> 1) * 32;
    const unsigned short* Ma = M + ((size_t)b << 20) + ((size_t)(mt * 32 + rloc + m) << 10) + q * 8;
    const unsigned short* W0 = WT + ((size_t)b << 16) + ((size_t)(nbase + m) << 10) + q * 8;
    const unsigned short* W1 = W0 + (16 << 10);
    f32x4 acc0 = {0.f, 0.f, 0.f, 0.f}, acc1 = {0.f, 0.f, 0.f, 0.f};
#pragma unroll 4
    for (int k0 = 0; k0 < NN; k0 += 32) {
        short8 af = *(const short8*)(Ma + k0);
        short8 b0 = *(const short8*)(W0 + k0);
        short8 b1 = *(const short8*)(W1 + k0);
        acc0 = __builtin_amdgcn_mfma_f32_16x16x32_bf16(af, b0, acc0, 0, 0, 0);
        acc1 = __builtin_amdgcn_mfma_f32_16x16x32_bf16(af, b1, acc1, 0, 0, 0);
    }
#pragma unroll
    for (int r = 0; r < 4; ++r) {
        int lrow = rloc + q * 4 + r;
        int gm = mt * 32 + lrow;
        float a = sa[lrow];
        size_t base = (((size_t)b << 10) + gm) * DD;
        int n0 = nbase + m;
        out[base + n0]      = fmaf(a, acc0[r], V[base + n0]);
        out[base + n0 + 16] = fmaf(a, acc1[r], V[base + n0 + 16]);
    }
}

extern "C" void kernel_launch(void* const* d_in, const int* in_sizes, int n_in,
                              void* d_out, int out_size, void* d_ws, size_t ws_size,
                              hipStream_t stream) {
    const float* q = (const float*)d_in[0];
    const float* k = (const float*)d_in[1];
    const float* V = (const float*)d_in[2];
    float* out = (float*)d_out;

    char* ws = (char*)d_ws;
    const size_t MB16 = (size_t)BB * NN * NN * sizeof(unsigned short);   // 16 MB
    unsigned short* M  = (unsigned short*)ws;
    unsigned short* MT = (unsigned short*)(ws + MB16);
    unsigned short* WT = MT;                  // MT is dead after sink; reuse (1 MB)
    float* u   = (float*)(ws + 2 * MB16);
    float* v   = u + BB * NN;                 // 8192 floats
    float* err = v + BB * NN;                 // 1024 floats (b*128+t)
    unsigned* cnt = (unsigned*)(err + 1024);  // 2048 u32 (b*256+p)
    unsigned* pub = cnt + 2048;               // 128 u32 (t)

    size_t zbytes = (size_t)(2 * BB * NN + 1024 + 2048 + 128) * 4;
    hipMemsetAsync(u, 0, zbytes, stream);

    cost_kernel<<<dim3(16, 16, 8), 256, 0, stream>>>(q, k, M, MT);

    float eln = EPSF * logf(1.0f / NN + 1e-8f);
    // REGULAR launch (single variable vs R9): barrier is hand-rolled, co-residency
    // is de-facto guaranteed at 256 blocks / 256 CUs (128 VGPR, 5.6KB LDS).
    // Failure mode if placement ever splits: visible hang, not silent corruption.
    sink_coop<<<dim3(NBLK), dim3(256), 0, stream>>>(M, MT, u, v, err, cnt, pub, eln);

    wt_kernel<<<128, 256, 0, stream>>>(V, v, WT);
    gemm_final<<<256, 256, 0, stream>>>(M, WT, u, V, out);
}